// Round 1
// baseline (190.652 us; speedup 1.0000x reference)
//
#include <hip/hip_runtime.h>

// Segment mean-pooling: feats [B,S,H] f32, segment_ids [B,S] i32 sorted
// non-decreasing in [0,G). Outputs flat-concat: grouped [B,G,H] f32, then
// counts [B,G] written as float values.
#define BB 8
#define SS 8192
#define HH 512
#define GG 1024
#define GPB 4   // groups per block

typedef float f32x4 __attribute__((ext_vector_type(4)));

// Single fused kernel: one block per (b, 4 consecutive groups).
// Group boundaries are found in-block by per-lane binary search over the
// sorted ids row (max 13 L1/L2-hit broadcast loads) -- this removes the
// separate seg_offsets dispatch, its workspace round-trip, and the
// inter-kernel dependency drain.
// Main loop: 128 lanes * float4 = 2048B = full H row, perfectly coalesced
// per token. 4-deep unroll for MLP; nontemporal loads/stores (pure
// streaming, no reuse).
__global__ __launch_bounds__(128) void group_mean_fused(
    const f32x4* __restrict__ feats,
    const int*   __restrict__ ids,
    f32x4*       __restrict__ grouped,
    float*       __restrict__ counts)
{
    const int g0 = blockIdx.x * GPB;
    const int b  = blockIdx.y;
    const int t  = threadIdx.x;   // 0..127
    const int lane = t & 63;

    const int* __restrict__ row = ids + (size_t)b * SS;

    // lower_bound(row, g) for g = g0 + lane (clamped at g0+GPB so all 64
    // lanes run the same code; lanes 0..GPB hold the GPB+1 boundaries).
    // Loop trip count <= 13 (SS = 2^13); lanes diverge by at most 1 iter.
    const int g = g0 + (lane < GPB ? lane : GPB);
    int lo = 0, hi = SS;
    while (lo < hi) {
        const int mid = (lo + hi) >> 1;   // mid in [lo, hi-1] -> always in-bounds
        if (row[mid] < g) lo = mid + 1; else hi = mid;
    }
    // lo == first index with row[lo] >= g (== SS if g > all ids).

    int o[GPB + 1];
    #pragma unroll
    for (int i = 0; i <= GPB; ++i) o[i] = __shfl(lo, i);

    const f32x4* __restrict__ fb = feats + (size_t)b * SS * (HH / 4);

    #pragma unroll
    for (int i = 0; i < GPB; ++i) {
        const int lo_i = o[i], hi_i = o[i + 1];
        const int n = hi_i - lo_i;
        f32x4 a0 = 0.f, a1 = 0.f, a2 = 0.f, a3 = 0.f;
        int s = lo_i;
        for (; s + 3 < hi_i; s += 4) {
            f32x4 v0 = __builtin_nontemporal_load(&fb[(size_t)(s    ) * (HH / 4) + t]);
            f32x4 v1 = __builtin_nontemporal_load(&fb[(size_t)(s + 1) * (HH / 4) + t]);
            f32x4 v2 = __builtin_nontemporal_load(&fb[(size_t)(s + 2) * (HH / 4) + t]);
            f32x4 v3 = __builtin_nontemporal_load(&fb[(size_t)(s + 3) * (HH / 4) + t]);
            a0 += v0; a1 += v1; a2 += v2; a3 += v3;
        }
        for (; s < hi_i; ++s) {
            a0 += __builtin_nontemporal_load(&fb[(size_t)s * (HH / 4) + t]);
        }
        const float inv = (n > 0) ? (1.0f / (float)n) : 0.0f;
        f32x4 r = ((a0 + a1) + (a2 + a3)) * inv;
        __builtin_nontemporal_store(r, &grouped[((size_t)b * GG + g0 + i) * (HH / 4) + t]);
        if (t == 0) counts[(size_t)b * GG + g0 + i] = (float)n;
    }
}

extern "C" void kernel_launch(void* const* d_in, const int* in_sizes, int n_in,
                              void* d_out, int out_size, void* d_ws, size_t ws_size,
                              hipStream_t stream) {
    const float* feats = (const float*)d_in[0];
    const int*   ids   = (const int*)d_in[1];
    float* grouped = (float*)d_out;
    float* counts  = grouped + (size_t)BB * GG * HH;

    dim3 grid(GG / GPB, BB);
    group_mean_fused<<<grid, 128, 0, stream>>>((const f32x4*)feats, ids,
                                               (f32x4*)grouped, counts);
}